// Round 1
// baseline (180.252 us; speedup 1.0000x reference)
//
#include <hip/hip_runtime.h>
#include <math.h>

#define E_ 256
#define W_ 20
#define S_ 5
#define Q_ 300
#define D_ 512
#define ALPHA_ 37.0f

// LDS: 20*512*4 = 40960 (shot_sum, later proto)
//    + 20*300*4 = 24000 (weights [w][q], later logits [q][w])
//    + 2*20*4   = 160   (m2, pinv)          => 65120 B <= 64 KiB static
__global__ __launch_bounds__(512) void fused_proto_kernel(
    const float* __restrict__ xs,      // [E,W,S,D]
    const float* __restrict__ xq,      // [E,Q,D]
    const float* __restrict__ temp_p,  // scalar
    float* __restrict__ out)           // [E,Q,W]
{
    __shared__ __align__(16) float s_sum[W_][D_];   // shot_sum -> proto
    __shared__ __align__(16) float s_buf[W_ * Q_];  // -dist -> weights -> logits[q*W+w]
    __shared__ float s_m2[W_];
    __shared__ float s_pinv[W_];

    const int e    = blockIdx.x;
    const int tid  = threadIdx.x;      // 0..511
    const int lane = tid & 63;
    const int wv   = tid >> 6;         // wave 0..7

    const float* xse = xs + (size_t)e * (W_ * S_ * D_);
    const float* xqe = xq + (size_t)e * (Q_ * D_);

    // ---------------- Phase 1: shot_sum into LDS (d = tid) ----------------
    #pragma unroll
    for (int w = 0; w < W_; ++w) {
        float a = 0.f;
        #pragma unroll
        for (int s = 0; s < S_; ++s) a += xse[(w * S_ + s) * D_ + tid];
        s_sum[w][tid] = a;
    }
    __syncthreads();

    // ---------------- Phase 2: m2[w] = ||mean_w||^2 = sumsq(shot_sum)/25 ----
    for (int w = wv; w < W_; w += 8) {
        float p = 0.f;
        for (int d = lane; d < D_; d += 64) { float v = s_sum[w][d]; p += v * v; }
        #pragma unroll
        for (int off = 32; off; off >>= 1) p += __shfl_xor(p, off);
        if (lane == 0) s_m2[w] = p * (1.f / (S_ * S_));
    }
    __syncthreads();

    // ---------------- Phase 3: dots -> -dist into s_buf[w*Q+q] -------------
    // 16-lane groups; each wave does 4 q at a time; 8 waves -> 32 q/iter.
    {
        const int g  = lane >> 4;      // group 0..3
        const int li = lane & 15;      // lane in group
        for (int qb = 0; qb < 320; qb += 32) {
            const int q   = qb + wv * 4 + g;
            const bool act = (q < Q_);
            float dot[W_];
            #pragma unroll
            for (int w = 0; w < W_; ++w) dot[w] = 0.f;
            float q2 = 0.f;
            if (act) {
                const float4* qrow = reinterpret_cast<const float4*>(xqe + q * D_);
                #pragma unroll
                for (int k = 0; k < 8; ++k) {
                    const float4 qv = qrow[k * 16 + li];   // d = 64k + 4*li
                    q2 += qv.x * qv.x + qv.y * qv.y + qv.z * qv.z + qv.w * qv.w;
                    #pragma unroll
                    for (int w = 0; w < W_; ++w) {
                        const float4 sv =
                            reinterpret_cast<const float4*>(s_sum[w])[k * 16 + li];
                        dot[w] += qv.x * sv.x + qv.y * sv.y + qv.z * sv.z + qv.w * sv.w;
                    }
                }
            }
            // reduce across the 16-lane group
            #pragma unroll
            for (int off = 1; off < 16; off <<= 1) {
                q2 += __shfl_xor(q2, off);
                #pragma unroll
                for (int w = 0; w < W_; ++w) dot[w] += __shfl_xor(dot[w], off);
            }
            if (act && li == 0) {
                #pragma unroll
                for (int w = 0; w < W_; ++w) {
                    float d2 = s_m2[w] + q2 - (2.f / S_) * dot[w];
                    d2 = d2 > 0.f ? d2 : 0.f;
                    s_buf[w * Q_ + q] = -sqrtf(d2);
                }
            }
        }
    }
    __syncthreads();

    // ---------------- Phase 4: softmax over q per w-row ---------------------
    for (int w = wv; w < W_; w += 8) {
        float mx = -1e30f;
        for (int q = lane; q < Q_; q += 64) mx = fmaxf(mx, s_buf[w * Q_ + q]);
        #pragma unroll
        for (int off = 32; off; off >>= 1) mx = fmaxf(mx, __shfl_xor(mx, off));
        float sm = 0.f;
        for (int q = lane; q < Q_; q += 64) {
            float ex = __expf(s_buf[w * Q_ + q] - mx);
            s_buf[w * Q_ + q] = ex;
            sm += ex;
        }
        #pragma unroll
        for (int off = 32; off; off >>= 1) sm += __shfl_xor(sm, off);
        const float inv = 1.f / sm;
        for (int q = lane; q < Q_; q += 64) s_buf[w * Q_ + q] *= inv;
    }
    __syncthreads();

    // ---------------- Phase 5: pooled (col d = tid) + proto in-place --------
    {
        float acc[W_];
        #pragma unroll
        for (int w = 0; w < W_; ++w) acc[w] = 0.f;
        for (int q0 = 0; q0 < Q_; q0 += 4) {      // 300 % 4 == 0
            const float qv0 = xqe[(q0 + 0) * D_ + tid];
            const float qv1 = xqe[(q0 + 1) * D_ + tid];
            const float qv2 = xqe[(q0 + 2) * D_ + tid];
            const float qv3 = xqe[(q0 + 3) * D_ + tid];
            #pragma unroll
            for (int w = 0; w < W_; ++w) {
                // aligned: (w*300 + q0) % 4 == 0, base 16B-aligned
                const float4 wt = *reinterpret_cast<const float4*>(&s_buf[w * Q_ + q0]);
                acc[w] += wt.x * qv0 + wt.y * qv1 + wt.z * qv2 + wt.w * qv3;
            }
        }
        #pragma unroll
        for (int w = 0; w < W_; ++w)
            s_sum[w][tid] = (s_sum[w][tid] + ALPHA_ * acc[w]) * (1.f / (S_ + ALPHA_));
    }
    __syncthreads();

    // ---------------- Phase 6: proto inverse norms --------------------------
    for (int w = wv; w < W_; w += 8) {
        float p = 0.f;
        for (int d = lane; d < D_; d += 64) { float v = s_sum[w][d]; p += v * v; }
        #pragma unroll
        for (int off = 32; off; off >>= 1) p += __shfl_xor(p, off);
        if (lane == 0) s_pinv[w] = 1.f / fmaxf(sqrtf(p), 1e-12f);
    }
    __syncthreads();

    // ---------------- Phase 7: logits dots into s_buf[q*W+w] ----------------
    {
        const int g  = lane >> 4;
        const int li = lane & 15;
        const float temp = *temp_p;
        for (int qb = 0; qb < 320; qb += 32) {
            const int q   = qb + wv * 4 + g;
            const bool act = (q < Q_);
            float dot[W_];
            #pragma unroll
            for (int w = 0; w < W_; ++w) dot[w] = 0.f;
            float q2 = 0.f;
            if (act) {
                const float4* qrow = reinterpret_cast<const float4*>(xqe + q * D_);
                #pragma unroll
                for (int k = 0; k < 8; ++k) {
                    const float4 qv = qrow[k * 16 + li];
                    q2 += qv.x * qv.x + qv.y * qv.y + qv.z * qv.z + qv.w * qv.w;
                    #pragma unroll
                    for (int w = 0; w < W_; ++w) {
                        const float4 sv =
                            reinterpret_cast<const float4*>(s_sum[w])[k * 16 + li];
                        dot[w] += qv.x * sv.x + qv.y * sv.y + qv.z * sv.z + qv.w * sv.w;
                    }
                }
            }
            #pragma unroll
            for (int off = 1; off < 16; off <<= 1) {
                q2 += __shfl_xor(q2, off);
                #pragma unroll
                for (int w = 0; w < W_; ++w) dot[w] += __shfl_xor(dot[w], off);
            }
            if (act && li == 0) {
                const float scale = temp / fmaxf(sqrtf(q2), 1e-12f);
                #pragma unroll
                for (int w = 0; w < W_; ++w)
                    s_buf[q * W_ + w] = scale * s_pinv[w] * dot[w];
            }
        }
    }
    __syncthreads();

    // ---------------- Phase 8: coalesced store ------------------------------
    float* oute = out + (size_t)e * (Q_ * W_);
    for (int i = tid; i < Q_ * W_; i += 512) oute[i] = s_buf[i];
}

extern "C" void kernel_launch(void* const* d_in, const int* in_sizes, int n_in,
                              void* d_out, int out_size, void* d_ws, size_t ws_size,
                              hipStream_t stream) {
    const float* xs = (const float*)d_in[0];
    const float* xq = (const float*)d_in[1];
    const float* tp = (const float*)d_in[2];
    fused_proto_kernel<<<E_, 512, 0, stream>>>(xs, xq, tp, (float*)d_out);
}

// Round 4
// 120.265 us; speedup vs baseline: 1.4988x; 1.4988x over previous
//
#include <hip/hip_runtime.h>
#include <math.h>

#define E_ 256
#define W_ 20
#define S_ 5
#define Q_ 300
#define D_ 512
#define ALPHA_ 37.0f
#define QCH 64
#define NCH 5            // chunks: 64,64,64,64,44
#define QPAD 304

typedef __attribute__((ext_vector_type(8))) short bf16x8;
typedef __attribute__((ext_vector_type(4))) float f32x4;
typedef __attribute__((ext_vector_type(4))) unsigned int u32x4;

// dynamic LDS layout (bytes)
#define OFF_SS   0         // 32 rows x 1024B : shot_sum bf16 (XOR-swizzled) -> later proto_n bf16
#define OFF_XQ   32768     // 64 rows x 1024B : xq chunk bf16 (XOR-swizzled)
#define OFF_BUF  98304     // f32 [20][304]   : -dist -> weights
#define OFF_Q2   122624    // f32 [320]       : ||q||^2  (320: chunk-4 staging writes 300..319)
#define OFF_M2   123904    // f32 [32]        : ||mean||^2 -> later 1/||proto||
#define OFF_RED  124032    // f32 [8][20]     : norm partials
#define LDS_BYTES 124672

__device__ __forceinline__ unsigned short f2bf(float x) {
    unsigned int u = __builtin_bit_cast(unsigned int, x);
    u += 0x7fffu + ((u >> 16) & 1u);          // RNE
    return (unsigned short)(u >> 16);
}
__device__ __forceinline__ float bf2f(unsigned short h) {
    unsigned int u = ((unsigned int)h) << 16;
    return __builtin_bit_cast(float, u);
}

// MFMA fragment read: row-major [row][512 bf16], row stride 1024B,
// 16B chunks XOR-swizzled by (row&7). k0 = bf16 index, multiple of 8.
__device__ __forceinline__ bf16x8 ldfrag(const char* base, int row, int k0) {
    const int phys = (k0 >> 3) ^ (row & 7);
    return *reinterpret_cast<const bf16x8*>(base + row * 1024 + phys * 16);
}

// Stage one q-chunk of x_query into LDS as swizzled bf16; optionally q2.
__device__ __forceinline__ void stage_chunk(const float4* xq4, char* s_xq, float* s_q2,
                                            int c, int qcount, int tid, bool write_q2) {
    const int qr = tid >> 3;          // row within chunk 0..63
    const int i  = tid & 7;
    const bool valid = qr < qcount;
    const int qg = c * QCH + qr;
    float q2 = 0.f;
    const float4* row4 = xq4 + (size_t)(valid ? qg : 0) * (D_ / 4);
    #pragma unroll
    for (int j = 0; j < 8; ++j) {
        const int ch = i + 8 * j;     // 16B chunk index: d = ch*8 .. ch*8+7
        float4 a = valid ? row4[2 * ch]     : make_float4(0.f, 0.f, 0.f, 0.f);
        float4 b = valid ? row4[2 * ch + 1] : make_float4(0.f, 0.f, 0.f, 0.f);
        q2 += a.x * a.x + a.y * a.y + a.z * a.z + a.w * a.w
            + b.x * b.x + b.y * b.y + b.z * b.z + b.w * b.w;
        u32x4 v;
        v[0] = (unsigned int)f2bf(a.x) | ((unsigned int)f2bf(a.y) << 16);
        v[1] = (unsigned int)f2bf(a.z) | ((unsigned int)f2bf(a.w) << 16);
        v[2] = (unsigned int)f2bf(b.x) | ((unsigned int)f2bf(b.y) << 16);
        v[3] = (unsigned int)f2bf(b.z) | ((unsigned int)f2bf(b.w) << 16);
        *reinterpret_cast<u32x4*>(s_xq + qr * 1024 + ((ch ^ (qr & 7)) << 4)) = v;
    }
    if (write_q2) {
        q2 += __shfl_xor(q2, 1);
        q2 += __shfl_xor(q2, 2);
        q2 += __shfl_xor(q2, 4);
        if (i == 0) s_q2[qg] = valid ? q2 : 0.f;   // qg up to 319; s_q2 sized 320
    }
}

__global__ __launch_bounds__(512) void fused4(const float* __restrict__ xs,
                                              const float* __restrict__ xq,
                                              const float* __restrict__ temp_p,
                                              float* __restrict__ out) {
    extern __shared__ char smem[];
    char*  s_ss  = smem + OFF_SS;
    char*  s_xq  = smem + OFF_XQ;
    float* s_buf = (float*)(smem + OFF_BUF);
    float* s_q2  = (float*)(smem + OFF_Q2);
    float* s_m2  = (float*)(smem + OFF_M2);
    float* s_red = (float*)(smem + OFF_RED);

    const int e    = blockIdx.x;
    const int tid  = threadIdx.x;
    const int lane = tid & 63;
    const int wv   = tid >> 6;
    const int ln15 = lane & 15;
    const int hi   = lane >> 4;

    const float*  xse = xs + (size_t)e * (W_ * S_ * D_);
    const float*  xqe = xq + (size_t)e * (Q_ * D_);
    const float4* xq4 = (const float4*)xqe;
    const float   temp = *temp_p;

    // ---- P0: zero pad rows 20..31 of s_ss ----
    for (int idx = tid; idx < 12 * 64; idx += 512) {
        const int row = 20 + (idx >> 6), ch = idx & 63;
        u32x4 z = {0u, 0u, 0u, 0u};
        *reinterpret_cast<u32x4*>(s_ss + row * 1024 + ch * 16) = z;
    }
    // ---- P1: shot_sum -> s_ss bf16 (d = tid) ----
    {
        const int chb = tid >> 3;
        #pragma unroll
        for (int w = 0; w < W_; ++w) {
            float a = 0.f;
            #pragma unroll
            for (int s = 0; s < S_; ++s) a += xse[(w * S_ + s) * D_ + tid];
            *(unsigned short*)(s_ss + w * 1024 + ((chb ^ (w & 7)) << 4) + (tid & 7) * 2) = f2bf(a);
        }
    }
    __syncthreads();

    // ---- P2: m2[w] = ||shot_mean||^2 from bf16 shot_sum ----
    for (int w = wv; w < W_; w += 8) {
        bf16x8 v = *reinterpret_cast<const bf16x8*>(s_ss + w * 1024 + ((lane ^ (w & 7)) << 4));
        float p = 0.f;
        #pragma unroll
        for (int j = 0; j < 8; ++j) { float f = bf2f((unsigned short)v[j]); p += f * f; }
        #pragma unroll
        for (int off = 32; off; off >>= 1) p += __shfl_xor(p, off);
        if (lane == 0) s_m2[w] = p * (1.f / (S_ * S_));
    }
    __syncthreads();

    // ---- P3: dist via MFMA per q-chunk -> s_buf[w][q] = -dist ----
    for (int c = 0; c < NCH; ++c) {
        const int qcount = (c == 4) ? (Q_ - 4 * QCH) : QCH;
        stage_chunk(xq4, s_xq, s_q2, c, qcount, tid, true);
        __syncthreads();
        const int mtile = wv >> 2, ntile = wv & 3;   // 2 x 4 tiles
        f32x4 acc = {0.f, 0.f, 0.f, 0.f};
        const int arow = mtile * 16 + ln15;          // w row of shot_sum (M side)
        const int brow = ntile * 16 + ln15;          // q row of chunk    (N side)
        #pragma unroll
        for (int k = 0; k < 16; ++k) {
            bf16x8 a = ldfrag(s_ss, arow, k * 32 + hi * 8);
            bf16x8 b = ldfrag(s_xq, brow, k * 32 + hi * 8);
            acc = __builtin_amdgcn_mfma_f32_16x16x32_bf16(a, b, acc, 0, 0, 0);
        }
        // C/D layout (HW-probe-confirmed, m89): col(N)=ln15, row(M)=hi*4+r
        const int qloc = ntile * 16 + ln15;
        if (qloc < qcount) {
            const int qg = c * QCH + qloc;
            const float q2v = s_q2[qg];
            #pragma unroll
            for (int r = 0; r < 4; ++r) {
                const int w = mtile * 16 + hi * 4 + r;
                if (w < W_) {
                    float d2 = s_m2[w] + q2v - 0.4f * acc[r];
                    s_buf[w * QPAD + qg] = -sqrtf(fmaxf(d2, 0.f));
                }
            }
        }
        __syncthreads();
    }

    // ---- P4: softmax over q per w ----
    for (int w = wv; w < W_; w += 8) {
        float mx = -1e30f;
        for (int q = lane; q < Q_; q += 64) mx = fmaxf(mx, s_buf[w * QPAD + q]);
        #pragma unroll
        for (int off = 32; off; off >>= 1) mx = fmaxf(mx, __shfl_xor(mx, off));
        float sm = 0.f;
        for (int q = lane; q < Q_; q += 64) {
            float ex = __expf(s_buf[w * QPAD + q] - mx);
            s_buf[w * QPAD + q] = ex;
            sm += ex;
        }
        #pragma unroll
        for (int off = 32; off; off >>= 1) sm += __shfl_xor(sm, off);
        const float inv = 1.f / sm;
        for (int q = lane; q < Q_; q += 64) s_buf[w * QPAD + q] *= inv;
    }
    __syncthreads();

    // ---- P5: pooled (d = tid, f32) + proto + norms + proto_n -> s_ss bf16 ----
    {
        float pr[W_];
        #pragma unroll
        for (int w = 0; w < W_; ++w) pr[w] = 0.f;
        for (int q0 = 0; q0 < Q_; q0 += 4) {
            const float qv0 = xqe[(q0 + 0) * D_ + tid];
            const float qv1 = xqe[(q0 + 1) * D_ + tid];
            const float qv2 = xqe[(q0 + 2) * D_ + tid];
            const float qv3 = xqe[(q0 + 3) * D_ + tid];
            #pragma unroll
            for (int w = 0; w < W_; ++w) {
                const float4 wt = *reinterpret_cast<const float4*>(&s_buf[w * QPAD + q0]);
                pr[w] += wt.x * qv0 + wt.y * qv1 + wt.z * qv2 + wt.w * qv3;
            }
        }
        const int chb = tid >> 3;
        #pragma unroll
        for (int w = 0; w < W_; ++w) {
            unsigned short h =
                *(unsigned short*)(s_ss + w * 1024 + ((chb ^ (w & 7)) << 4) + (tid & 7) * 2);
            pr[w] = (bf2f(h) + ALPHA_ * pr[w]) * (1.f / (S_ + ALPHA_));
        }
        #pragma unroll
        for (int w = 0; w < W_; ++w) {
            float p = pr[w] * pr[w];
            #pragma unroll
            for (int off = 32; off; off >>= 1) p += __shfl_xor(p, off);
            if (lane == 0) s_red[wv * W_ + w] = p;
        }
        __syncthreads();
        if (tid < W_) {
            float p = 0.f;
            #pragma unroll
            for (int k = 0; k < 8; ++k) p += s_red[k * W_ + tid];
            s_m2[tid] = 1.f / fmaxf(sqrtf(p), 1e-12f);   // reuse as 1/||proto||
        }
        __syncthreads();
        #pragma unroll
        for (int w = 0; w < W_; ++w) {
            *(unsigned short*)(s_ss + w * 1024 + ((chb ^ (w & 7)) << 4) + (tid & 7) * 2) =
                f2bf(pr[w] * s_m2[w]);
        }
        __syncthreads();
    }

    // ---- P6: logits via MFMA per q-chunk; direct global store ----
    for (int c = 0; c < NCH; ++c) {
        const int qcount = (c == 4) ? (Q_ - 4 * QCH) : QCH;
        stage_chunk(xq4, s_xq, s_q2, c, qcount, tid, false);
        __syncthreads();
        const int mtile = wv >> 1, ntile = wv & 1;   // 4 x 2 tiles
        f32x4 acc = {0.f, 0.f, 0.f, 0.f};
        const int arow = mtile * 16 + ln15;          // q row (M side)
        const int brow = ntile * 16 + ln15;          // w row (N side, proto_n)
        #pragma unroll
        for (int k = 0; k < 16; ++k) {
            bf16x8 a = ldfrag(s_xq, arow, k * 32 + hi * 8);
            bf16x8 b = ldfrag(s_ss, brow, k * 32 + hi * 8);
            acc = __builtin_amdgcn_mfma_f32_16x16x32_bf16(a, b, acc, 0, 0, 0);
        }
        const int w = ntile * 16 + ln15;             // N side
        if (w < W_) {
            #pragma unroll
            for (int r = 0; r < 4; ++r) {
                const int qloc = mtile * 16 + hi * 4 + r;   // M side
                if (qloc < qcount) {
                    const int qg = c * QCH + qloc;
                    const float scale = temp / fmaxf(sqrtf(s_q2[qg]), 1e-12f);
                    out[(size_t)e * (Q_ * W_) + qg * W_ + w] = scale * acc[r];
                }
            }
        }
        __syncthreads();
    }
}

extern "C" void kernel_launch(void* const* d_in, const int* in_sizes, int n_in,
                              void* d_out, int out_size, void* d_ws, size_t ws_size,
                              hipStream_t stream) {
    const float* xs = (const float*)d_in[0];
    const float* xq = (const float*)d_in[1];
    const float* tp = (const float*)d_in[2];
    hipFuncSetAttribute(reinterpret_cast<const void*>(fused4),
                        hipFuncAttributeMaxDynamicSharedMemorySize, LDS_BYTES);
    fused4<<<E_, 512, LDS_BYTES, stream>>>(xs, xq, tp, (float*)d_out);
}

// Round 5
// 108.986 us; speedup vs baseline: 1.6539x; 1.1035x over previous
//
#include <hip/hip_runtime.h>
#include <math.h>

#define E_ 256
#define W_ 20
#define S_ 5
#define Q_ 300
#define D_ 512
#define ALPHA_ 37.0f
#define QCH 64
#define NCH 5            // chunks: 64,64,64,64,44
#define QPAD 304

typedef __attribute__((ext_vector_type(8))) short bf16x8;
typedef __attribute__((ext_vector_type(4))) float f32x4;
typedef __attribute__((ext_vector_type(2))) unsigned int u32x2;
typedef __attribute__((ext_vector_type(4))) unsigned int u32x4;

// dynamic LDS layout (bytes) — identical to round 4 (verified)
#define OFF_SS   0         // 32 rows x 1024B : shot_sum bf16 (XOR-swizzled) -> later proto_n bf16
#define OFF_XQ   32768     // 64 rows x 1024B : xq chunk bf16 (XOR-swizzled)
#define OFF_BUF  98304     // f32 [20][304]   : -dist -> weights
#define OFF_Q2   122624    // f32 [320]       : ||q||^2  (320: chunk-4 staging writes 300..319)
#define OFF_M2   123904    // f32 [32]        : ||mean||^2 -> later 1/||proto||
#define OFF_RED  124032    // f32 [8][20]     : norm partials
#define LDS_BYTES 124672

__device__ __forceinline__ unsigned short f2bf(float x) {
    unsigned int u = __builtin_bit_cast(unsigned int, x);
    u += 0x7fffu + ((u >> 16) & 1u);          // RNE
    return (unsigned short)(u >> 16);
}
__device__ __forceinline__ float bf2f(unsigned short h) {
    unsigned int u = ((unsigned int)h) << 16;
    return __builtin_bit_cast(float, u);
}

// MFMA fragment read: row-major [row][512 bf16], row stride 1024B,
// 16B chunks XOR-swizzled by (row&7). k0 = bf16 index, multiple of 8.
__device__ __forceinline__ bf16x8 ldfrag(const char* base, int row, int k0) {
    const int phys = (k0 >> 3) ^ (row & 7);
    return *reinterpret_cast<const bf16x8*>(base + row * 1024 + phys * 16);
}

// ---- T14 async-STAGE split: issue-early (load) / write-late (convert+LDS) ----
__device__ __forceinline__ void stage_load(const float4* xq4, int c, int qcount,
                                           int tid, float4* r) {
    const int qr = tid >> 3;
    const int i  = tid & 7;
    const int qg = c * QCH + ((qr < qcount) ? qr : 0);   // clamp: in-bounds dummy row
    const float4* row4 = xq4 + (size_t)qg * (D_ / 4);
    #pragma unroll
    for (int j = 0; j < 8; ++j) {
        const int ch = i + 8 * j;
        r[2 * j]     = row4[2 * ch];
        r[2 * j + 1] = row4[2 * ch + 1];
    }
}

template <bool WQ2>
__device__ __forceinline__ void stage_write(const float4* r, char* s_xq, float* s_q2,
                                            int c, int qcount, int tid) {
    const int qr = tid >> 3;
    const int i  = tid & 7;
    const bool valid = qr < qcount;
    float q2 = 0.f;
    #pragma unroll
    for (int j = 0; j < 8; ++j) {
        const int ch = i + 8 * j;
        float4 a = valid ? r[2 * j]     : make_float4(0.f, 0.f, 0.f, 0.f);
        float4 b = valid ? r[2 * j + 1] : make_float4(0.f, 0.f, 0.f, 0.f);
        if (WQ2) {
            q2 += a.x * a.x + a.y * a.y + a.z * a.z + a.w * a.w
                + b.x * b.x + b.y * b.y + b.z * b.z + b.w * b.w;
        }
        u32x4 v;
        v[0] = (unsigned int)f2bf(a.x) | ((unsigned int)f2bf(a.y) << 16);
        v[1] = (unsigned int)f2bf(a.z) | ((unsigned int)f2bf(a.w) << 16);
        v[2] = (unsigned int)f2bf(b.x) | ((unsigned int)f2bf(b.y) << 16);
        v[3] = (unsigned int)f2bf(b.z) | ((unsigned int)f2bf(b.w) << 16);
        *reinterpret_cast<u32x4*>(s_xq + qr * 1024 + ((ch ^ (qr & 7)) << 4)) = v;
    }
    if (WQ2) {
        q2 += __shfl_xor(q2, 1);
        q2 += __shfl_xor(q2, 2);
        q2 += __shfl_xor(q2, 4);
        if (i == 0) s_q2[c * QCH + qr] = valid ? q2 : 0.f;   // s_q2 sized 320
    }
}

__global__ __launch_bounds__(512) void fused5(const float* __restrict__ xs,
                                              const float* __restrict__ xq,
                                              const float* __restrict__ temp_p,
                                              float* __restrict__ out) {
    extern __shared__ char smem[];
    char*  s_ss  = smem + OFF_SS;
    char*  s_xq  = smem + OFF_XQ;
    float* s_buf = (float*)(smem + OFF_BUF);
    float* s_q2  = (float*)(smem + OFF_Q2);
    float* s_m2  = (float*)(smem + OFF_M2);
    float* s_red = (float*)(smem + OFF_RED);

    const int e    = blockIdx.x;
    const int tid  = threadIdx.x;
    const int lane = tid & 63;
    const int wv   = tid >> 6;
    const int ln15 = lane & 15;
    const int hi   = lane >> 4;

    const float*  xse = xs + (size_t)e * (W_ * S_ * D_);
    const float*  xqe = xq + (size_t)e * (Q_ * D_);
    const float4* xq4 = (const float4*)xqe;
    const float   temp = *temp_p;

    float4 buf[16];                       // prefetch buffer, fully unrolled indices

    // ---- prefetch chunk 0 (hides under P0/P1/P2) ----
    stage_load(xq4, 0, QCH, tid, buf);

    // ---- P0: zero pad rows 20..31 of s_ss ----
    for (int idx = tid; idx < 12 * 64; idx += 512) {
        const int row = 20 + (idx >> 6), ch = idx & 63;
        u32x4 z = {0u, 0u, 0u, 0u};
        *reinterpret_cast<u32x4*>(s_ss + row * 1024 + ch * 16) = z;
    }
    // ---- P1: shot_sum -> s_ss bf16, float4-vectorized ----
    // 2560 outputs of 4 d each; idx -> (w = idx>>7, dq = idx&127, d = dq*4)
    #pragma unroll
    for (int it = 0; it < 5; ++it) {
        const int idx = it * 512 + tid;
        const int w   = idx >> 7;
        const int dq  = idx & 127;
        const float4* p0 = reinterpret_cast<const float4*>(xse + (w * S_) * D_ + dq * 4);
        float4 a = p0[0];
        #pragma unroll
        for (int s = 1; s < S_; ++s) {
            const float4 t = p0[s * (D_ / 4)];
            a.x += t.x; a.y += t.y; a.z += t.z; a.w += t.w;
        }
        u32x2 v;
        v[0] = (unsigned int)f2bf(a.x) | ((unsigned int)f2bf(a.y) << 16);
        v[1] = (unsigned int)f2bf(a.z) | ((unsigned int)f2bf(a.w) << 16);
        *reinterpret_cast<u32x2*>(s_ss + w * 1024 + (((dq >> 1) ^ (w & 7)) << 4) +
                                  (dq & 1) * 8) = v;
    }
    __syncthreads();

    // ---- P2: m2[w] = ||shot_mean||^2 from bf16 shot_sum ----
    for (int w = wv; w < W_; w += 8) {
        bf16x8 v = *reinterpret_cast<const bf16x8*>(s_ss + w * 1024 + ((lane ^ (w & 7)) << 4));
        float p = 0.f;
        #pragma unroll
        for (int j = 0; j < 8; ++j) { float f = bf2f((unsigned short)v[j]); p += f * f; }
        #pragma unroll
        for (int off = 32; off; off >>= 1) p += __shfl_xor(p, off);
        if (lane == 0) s_m2[w] = p * (1.f / (S_ * S_));
    }
    __syncthreads();

    // ---- P3: dist via MFMA per q-chunk (pipelined staging) ----
    for (int c = 0; c < NCH; ++c) {
        const int qcount = (c == 4) ? (Q_ - 4 * QCH) : QCH;
        stage_write<true>(buf, s_xq, s_q2, c, qcount, tid);
        __syncthreads();
        if (c + 1 < NCH)   // issue next chunk's loads; overlap with MFMA below
            stage_load(xq4, c + 1, (c + 1 == 4) ? (Q_ - 4 * QCH) : QCH, tid, buf);

        const int mtile = wv >> 2, ntile = wv & 3;   // 2 x 4 tiles
        f32x4 acc = {0.f, 0.f, 0.f, 0.f};
        const int arow = mtile * 16 + ln15;          // w row (M side)
        const int brow = ntile * 16 + ln15;          // q row (N side)
        #pragma unroll
        for (int k = 0; k < 16; ++k) {
            bf16x8 a = ldfrag(s_ss, arow, k * 32 + hi * 8);
            bf16x8 b = ldfrag(s_xq, brow, k * 32 + hi * 8);
            acc = __builtin_amdgcn_mfma_f32_16x16x32_bf16(a, b, acc, 0, 0, 0);
        }
        // C/D layout (HW-verified r3): col(N)=ln15, row(M)=hi*4+r
        const int qloc = ntile * 16 + ln15;
        if (qloc < qcount) {
            const int qg = c * QCH + qloc;
            const float q2v = s_q2[qg];
            #pragma unroll
            for (int r = 0; r < 4; ++r) {
                const int w = mtile * 16 + hi * 4 + r;
                if (w < W_) {
                    float d2 = s_m2[w] + q2v - 0.4f * acc[r];
                    s_buf[w * QPAD + qg] = -sqrtf(fmaxf(d2, 0.f));
                }
            }
        }
        __syncthreads();
    }

    // ---- P4: softmax over q per w ----
    for (int w = wv; w < W_; w += 8) {
        float mx = -1e30f;
        for (int q = lane; q < Q_; q += 64) mx = fmaxf(mx, s_buf[w * QPAD + q]);
        #pragma unroll
        for (int off = 32; off; off >>= 1) mx = fmaxf(mx, __shfl_xor(mx, off));
        float sm = 0.f;
        for (int q = lane; q < Q_; q += 64) {
            float ex = __expf(s_buf[w * QPAD + q] - mx);
            s_buf[w * QPAD + q] = ex;
            sm += ex;
        }
        #pragma unroll
        for (int off = 32; off; off >>= 1) sm += __shfl_xor(sm, off);
        const float inv = 1.f / sm;
        for (int q = lane; q < Q_; q += 64) s_buf[w * QPAD + q] *= inv;
    }
    __syncthreads();

    // ---- prefetch P6 chunk 0 (hides under the whole of P5) ----
    stage_load(xq4, 0, QCH, tid, buf);

    // ---- P5: pooled (d = tid, f32) + proto + norms + proto_n -> s_ss bf16 ----
    {
        float pr[W_];
        #pragma unroll
        for (int w = 0; w < W_; ++w) pr[w] = 0.f;
        for (int q0 = 0; q0 < Q_; q0 += 4) {
            const float qv0 = xqe[(q0 + 0) * D_ + tid];
            const float qv1 = xqe[(q0 + 1) * D_ + tid];
            const float qv2 = xqe[(q0 + 2) * D_ + tid];
            const float qv3 = xqe[(q0 + 3) * D_ + tid];
            #pragma unroll
            for (int w = 0; w < W_; ++w) {
                const float4 wt = *reinterpret_cast<const float4*>(&s_buf[w * QPAD + q0]);
                pr[w] += wt.x * qv0 + wt.y * qv1 + wt.z * qv2 + wt.w * qv3;
            }
        }
        const int chb = tid >> 3;
        #pragma unroll
        for (int w = 0; w < W_; ++w) {
            unsigned short h =
                *(unsigned short*)(s_ss + w * 1024 + ((chb ^ (w & 7)) << 4) + (tid & 7) * 2);
            pr[w] = (bf2f(h) + ALPHA_ * pr[w]) * (1.f / (S_ + ALPHA_));
        }
        #pragma unroll
        for (int w = 0; w < W_; ++w) {
            float p = pr[w] * pr[w];
            #pragma unroll
            for (int off = 32; off; off >>= 1) p += __shfl_xor(p, off);
            if (lane == 0) s_red[wv * W_ + w] = p;
        }
        __syncthreads();
        if (tid < W_) {
            float p = 0.f;
            #pragma unroll
            for (int k = 0; k < 8; ++k) p += s_red[k * W_ + tid];
            s_m2[tid] = 1.f / fmaxf(sqrtf(p), 1e-12f);   // reuse as 1/||proto||
        }
        __syncthreads();
        #pragma unroll
        for (int w = 0; w < W_; ++w) {
            *(unsigned short*)(s_ss + w * 1024 + ((chb ^ (w & 7)) << 4) + (tid & 7) * 2) =
                f2bf(pr[w] * s_m2[w]);
        }
        __syncthreads();
    }

    // ---- P6: logits via MFMA per q-chunk (pipelined staging); direct store ----
    for (int c = 0; c < NCH; ++c) {
        const int qcount = (c == 4) ? (Q_ - 4 * QCH) : QCH;
        stage_write<false>(buf, s_xq, s_q2, c, qcount, tid);
        __syncthreads();
        if (c + 1 < NCH)
            stage_load(xq4, c + 1, (c + 1 == 4) ? (Q_ - 4 * QCH) : QCH, tid, buf);

        const int mtile = wv >> 1, ntile = wv & 1;   // 4 x 2 tiles
        f32x4 acc = {0.f, 0.f, 0.f, 0.f};
        const int arow = mtile * 16 + ln15;          // q row (M side)
        const int brow = ntile * 16 + ln15;          // w row (N side, proto_n)
        #pragma unroll
        for (int k = 0; k < 16; ++k) {
            bf16x8 a = ldfrag(s_xq, arow, k * 32 + hi * 8);
            bf16x8 b = ldfrag(s_ss, brow, k * 32 + hi * 8);
            acc = __builtin_amdgcn_mfma_f32_16x16x32_bf16(a, b, acc, 0, 0, 0);
        }
        const int w = ntile * 16 + ln15;             // N side
        if (w < W_) {
            #pragma unroll
            for (int r = 0; r < 4; ++r) {
                const int qloc = mtile * 16 + hi * 4 + r;   // M side
                if (qloc < qcount) {
                    const int qg = c * QCH + qloc;
                    const float scale = temp / fmaxf(sqrtf(s_q2[qg]), 1e-12f);
                    out[(size_t)e * (Q_ * W_) + qg * W_ + w] = scale * acc[r];
                }
            }
        }
        __syncthreads();
    }
}

extern "C" void kernel_launch(void* const* d_in, const int* in_sizes, int n_in,
                              void* d_out, int out_size, void* d_ws, size_t ws_size,
                              hipStream_t stream) {
    const float* xs = (const float*)d_in[0];
    const float* xq = (const float*)d_in[1];
    const float* tp = (const float*)d_in[2];
    hipFuncSetAttribute(reinterpret_cast<const void*>(fused5),
                        hipFuncAttributeMaxDynamicSharedMemorySize, LDS_BYTES);
    fused5<<<E_, 512, LDS_BYTES, stream>>>(xs, xq, tp, (float*)d_out);
}